// Round 3
// baseline (189.371 us; speedup 1.0000x reference)
//
#include <hip/hip_runtime.h>

// SecureOptimizedBlockReLU (16,128,114,114) fp32 — 3-dispatch per-class split.
// ch 0-31 passthrough copy; ch 32-79 2x2 block sign; ch 80-127 4x4 (block
// row/col 28 are 2-wide at the 114 edge). sign = f32_block_sum > -1.0f, summed
// in the exact sequential order verified bit-exact R1-R6 (absmax 0.0).
//
// Evidence trail: R6 (strip-LDS, float4 streams, 65us) == R7 (one-shot regs,
// 66us) == R8 (persistent 8-deep MLP, 69us) -> neither barriers, nor latency,
// nor access width is the limiter; all plateau at 2.4 TB/s HBM / 3.2 logical.
// This round isolates per-class bandwidth with 3 dispatches, and gives B/C the
// same memory shape as a pure copy: whole-float4 chunks (2-row chunk = 912 B =
// 57 aligned float4; 4-row = 114), block sums assembled cross-lane via __shfl
// in the bit-exact order, masks redistributed via __shfl. No LDS, no barriers,
// no sub-16B accesses anywhere.
//   sbrelu_a: pure float4 grid-stride copy (the discriminator: if THIS runs at
//   ~3.2 TB/s logical, the plateau is environmental -> roofline evidence).

typedef float v4 __attribute__((ext_vector_type(4)));

#define PLANE     12996     // 114*114 floats
#define NA4       1663488   // class-A float4 total: 16 * 103968
#define A_PER_N   103968    // 32*12996/4 float4 per n
#define A_NSTRIDE 415872    // 128*12996/4 float4 per n
#define NU_B      43776     // 768 planes * 57 two-row chunks
#define NU_C      22272     // 768 planes * 29 chunks (28 four-row + 1 two-row)

// ---- class A: ch 0..31 pure float4 copy ----
__global__ __launch_bounds__(256) void sbrelu_a(const float* __restrict__ in,
                                                float* __restrict__ out) {
    const v4* __restrict__ vin = (const v4*)in;
    v4* __restrict__ vout = (v4*)out;
    int t = blockIdx.x * 256 + threadIdx.x;
    int S = gridDim.x * 256;
    for (int i = t; i < NA4; i += S) {
        int n = i / A_PER_N;
        int o = n * A_NSTRIDE + (i - n * A_PER_N);
        vout[o] = vin[o];
    }
}

// ---- class B: 2x2 blocks. One wave per 2-row chunk (57 float4, 16B-aligned).
// Lane l holds float4 #l (positions 4l..4l+3 of the 228-float chunk).
// Block b (cols 2b,2b+1): row0 pair in lane b/2 (.xy or .zw); row1 pair in
// lane 28+b/2 (.zw) or 29+b/2 (.xy). Lane l owns masks for blocks 2l, 2l+1.
__global__ __launch_bounds__(256) void sbrelu_b(const float* __restrict__ in,
                                                float* __restrict__ out) {
    const int lane = threadIdx.x & 63;
    const int u = blockIdx.x * 4 + (threadIdx.x >> 6);   // [0, NU_B)
    const int p = u / 57;
    const int rp = u - 57 * p;
    const int n = p / 48;
    const int c = 32 + (p - 48 * n);
    const size_t base = (size_t)(n * 128 + c) * PLANE + 228 * rp;
    const v4* __restrict__ ip = (const v4*)(in + base);
    v4* __restrict__ op = (v4*)(out + base);

    const int ll = (lane < 57) ? lane : 56;   // lanes 57-63: dup load, no store
    v4 v = ip[ll];

    // row-1 halves: block 2*lane needs lane+28 .z/.w; block 2*lane+1 needs lane+29 .x/.y
    float z28 = __shfl(v.z, (lane + 28) & 63);
    float w28 = __shfl(v.w, (lane + 28) & 63);
    float x29 = __shfl(v.x, (lane + 29) & 63);
    float y29 = __shfl(v.y, (lane + 29) & 63);

    float se = ((v.x + v.y) + z28) + w28;     // block 2*lane   (exact R1-R6 order)
    float so = ((v.z + v.w) + x29) + y29;     // block 2*lane+1
    float pe = (se > -1.0f) ? 1.0f : 0.0f;
    float po = (so > -1.0f) ? 1.0f : 0.0f;

    // masks for this lane's 4 stored floats: e01 -> mf, e23 -> ms.
    // l<=27: blocks 2l,2l+1 (own). l==28: blocks 56 (own even), 0 (lane0 even).
    // l>=29: blocks 2l-57 (odd, lane l-29), 2l-56 (even, lane l-28).
    float f_pe = __shfl(pe, (lane <= 28) ? lane : 0);
    float f_po = __shfl(po, (lane >= 29) ? lane - 29 : 0);
    float g_po = __shfl(po, (lane <= 27) ? lane : 0);
    float g_pe = __shfl(pe, (lane == 28) ? 0 : ((lane >= 29) ? lane - 28 : 0));
    float mf = (lane <= 28) ? f_pe : f_po;
    float ms = (lane <= 27) ? g_po : g_pe;

    if (lane < 57) {
        v4 o;
        o.x = v.x * mf; o.y = v.y * mf;
        o.z = v.z * ms; o.w = v.w * ms;
        op[ll] = o;
    }
}

// ---- class C: 4x4 blocks. One wave per chunk: ch<28 = 4 rows (114 float4,
// lane l holds #l and #57+l); ch==28 = rows 112-113 (57 float4, #l only).
// Block cw (cols 4cw..4cw+3; cw==28 is 2-wide): owner lane cw. Row quads:
// r0 = own v, r1 = (lane 28+cw).zw + (lane 29+cw).xy, r2 = own w,
// r3 = (lane 28+cw) w.zw + (lane 29+cw) w.xy.  (228 = 2*114 -> regs #l and
// #57+l have identical col phase, so one mask pair serves both stores.)
__global__ __launch_bounds__(256) void sbrelu_c(const float* __restrict__ in,
                                                float* __restrict__ out) {
    const int lane = threadIdx.x & 63;
    const int u = blockIdx.x * 4 + (threadIdx.x >> 6);   // [0, NU_C)
    const int p = u / 29;
    const int ch = u - 29 * p;
    const int n = p / 48;
    const int c = 80 + (p - 48 * n);
    const size_t base = (size_t)(n * 128 + c) * PLANE + 456 * ch;
    const v4* __restrict__ ip = (const v4*)(in + base);
    v4* __restrict__ op = (v4*)(out + base);
    const int ll = (lane < 57) ? lane : 56;
    const int s1 = (lane + 28) & 63;
    const int s2 = (lane + 29) & 63;
    const bool fullc = (ch != 28);            // wave-uniform

    v4 v, w;
    float msk;
    if (fullc) {
        v = ip[ll];
        w = ip[57 + ll];
        float az = __shfl(v.z, s1), aw = __shfl(v.w, s1);
        float bz = __shfl(w.z, s1), bw = __shfl(w.w, s1);
        float cx = __shfl(v.x, s2), cy = __shfl(v.y, s2);
        float dx = __shfl(w.x, s2), dy = __shfl(w.y, s2);
        float s = 0.0f;
        if (lane != 28) {                     // 4-wide block, rows 4ch..4ch+3
            s += v.x; s += v.y; s += v.z; s += v.w;   // row 0 (cols 4cw..+3)
            s += az;  s += aw;  s += cx;  s += cy;    // row 1
            s += w.x; s += w.y; s += w.z; s += w.w;   // row 2
            s += bz;  s += bw;  s += dx;  s += dy;    // row 3
        } else {                              // block-col 28: cols 112,113 only
            s += v.x; s += v.y;
            s += az;  s += aw;
            s += w.x; s += w.y;
            s += bz;  s += bw;
        }
        msk = (s > -1.0f) ? 1.0f : 0.0f;
    } else {
        v = ip[ll];
        float az = __shfl(v.z, s1), aw = __shfl(v.w, s1);
        float cx = __shfl(v.x, s2), cy = __shfl(v.y, s2);
        float s = 0.0f;
        if (lane != 28) {                     // rows 112,113 (2-tall blocks)
            s += v.x; s += v.y; s += v.z; s += v.w;   // row 112
            s += az;  s += aw;  s += cx;  s += cy;    // row 113
        } else {
            s += v.x; s += v.y;
            s += az;  s += aw;
        }
        msk = (s > -1.0f) ? 1.0f : 0.0f;
    }

    // masks for stored float4(s): e01 -> mf, e23 -> ms. Reg #l cols:
    // l<=27: all in block l (mf==ms==msk[l]). l==28: blocks 28 then 0 (wrap).
    // l>=29: blocks l-29 (e01), l-28 (e23). Same phase for reg #57+l.
    float mf = __shfl(msk, (lane <= 28) ? lane : lane - 29);
    float ms = __shfl(msk, (lane <= 27) ? lane : ((lane == 28) ? 0 : lane - 28));

    if (lane < 57) {
        v4 o;
        o.x = v.x * mf; o.y = v.y * mf;
        o.z = v.z * ms; o.w = v.w * ms;
        op[ll] = o;
        if (fullc) {
            v4 o2;
            o2.x = w.x * mf; o2.y = w.y * mf;
            o2.z = w.z * ms; o2.w = w.w * ms;
            op[57 + ll] = o2;
        }
    }
}

extern "C" void kernel_launch(void* const* d_in, const int* in_sizes, int n_in,
                              void* d_out, int out_size, void* d_ws, size_t ws_size,
                              hipStream_t stream) {
    const float* in = (const float*)d_in[0];
    float* out = (float*)d_out;
    sbrelu_a<<<2048, 256, 0, stream>>>(in, out);
    sbrelu_b<<<NU_B / 4, 256, 0, stream>>>(in, out);   // 10944 blocks
    sbrelu_c<<<NU_C / 4, 256, 0, stream>>>(in, out);   // 5568 blocks
}